// Round 1
// baseline (2146.155 us; speedup 1.0000x reference)
//
#include <hip/hip_runtime.h>
#include <math.h>

// Problem constants (from reference)
#define N_DEST 16000   // B * D_CNT
#define KN     32      // neighbors per dest
#define HIDN   128
#define NH     4
#define HD     32
#define SRCD   64
#define EDGED  16
#define XD     80      // SRCD + EDGED
#define PAD    132     // padded row stride for 128-wide LDS tiles (bank de-conflict)

__device__ __forceinline__ float gelu_exact(float x) {
    return 0.5f * x * (1.0f + erff(x * 0.70710678118654752440f));
}

__global__ __launch_bounds__(256, 2) void fused_gat_kernel(
    const float* __restrict__ src,    // (16000, 64)
    const float* __restrict__ dest,   // (16000, 64)
    const int*   __restrict__ adj,    // (32, 16000)
    const int*   __restrict__ mask,   // (16000, 32)  nonzero => masked out (-inf)
    const float* __restrict__ edges,  // (32, 16000, 16)
    const float* __restrict__ W_src,  // (128, 80)
    const float* __restrict__ b_src,  // (128)
    const float* __restrict__ W_dest, // (128, 64)
    const float* __restrict__ b_dest, // (128)
    const float* __restrict__ Wqkv,   // (384, 128)  rows 0-127 Q, 128-255 K, 256-383 V
    const float* __restrict__ bqkv,   // (384)
    const float* __restrict__ Wo,     // (128, 128)
    const float* __restrict__ bo,     // (128)
    const float* __restrict__ ln_g,   // (128)
    const float* __restrict__ ln_b,   // (128)
    float* __restrict__ out)          // (16000, 128)
{
    const int n   = blockIdx.x;
    const int tid = threadIdx.x;

    __shared__ __align__(16) float sx[KN][XD];       // gathered [src|edge] rows
    __shared__ __align__(16) float s_sin[KN][PAD];   // src_in (post-gelu)
    __shared__ __align__(16) float s_k[KN][PAD];
    __shared__ __align__(16) float s_v[KN][PAD];
    __shared__ __align__(16) float s_dest[HIDN];     // dest_in (post-gelu)
    __shared__ __align__(16) float s_q[HIDN];        // scaled q
    __shared__ __align__(16) float s_attn[NH * KN];  // scores then attn
    __shared__ __align__(16) float s_ctx[HIDN];
    __shared__ __align__(16) float s_out[HIDN];
    __shared__ float s_red[2];
    __shared__ float s_mx[NH], s_den[NH];

    // ---------------- phase 0: gather x rows + dest_in ----------------
    for (int i = tid; i < KN * XD; i += 256) {
        int k = i / XD;
        int c = i - k * XD;
        float val;
        if (c < SRCD) {
            int a = adj[k * N_DEST + n];          // 0 => zero-pad row
            val = (a == 0) ? 0.0f : src[(a - 1) * SRCD + c];
        } else {
            val = edges[(k * N_DEST + n) * EDGED + (c - SRCD)];
        }
        sx[k][c] = val;
    }
    if (tid < HIDN) {
        int j = tid;
        float acc = b_dest[j];
        const float4* w4 = (const float4*)(W_dest + j * SRCD);
        const float4* x4 = (const float4*)(dest + n * SRCD);
        #pragma unroll
        for (int c = 0; c < SRCD / 4; ++c) {
            float4 w = w4[c]; float4 x = x4[c];
            acc = fmaf(w.x, x.x, acc); acc = fmaf(w.y, x.y, acc);
            acc = fmaf(w.z, x.z, acc); acc = fmaf(w.w, x.w, acc);
        }
        s_dest[j] = gelu_exact(acc);
    }
    __syncthreads();

    // ---------------- phase 1: q projection, then GEMM-D (src_in) ----------------
    if (tid < HIDN) {
        int j = tid;
        float acc = bqkv[j];
        const float4* w4 = (const float4*)(Wqkv + j * HIDN);
        const float4* x4 = (const float4*)s_dest;
        #pragma unroll
        for (int c = 0; c < HIDN / 4; ++c) {
            float4 w = w4[c]; float4 x = x4[c];
            acc = fmaf(w.x, x.x, acc); acc = fmaf(w.y, x.y, acc);
            acc = fmaf(w.z, x.z, acc); acc = fmaf(w.w, x.w, acc);
        }
        s_q[j] = acc * 0.17677669529663688110f;  // 1/sqrt(32)
    }
    // GEMM-D: (32 x 80) @ (80 x 128) -> gelu -> s_sin.  4 rows x 4 cols per thread.
    {
        const int cg = tid & 31, rg = tid >> 5;
        const int col0 = cg * 4, row0 = rg * 4;
        float acc[4][4];
        #pragma unroll
        for (int r = 0; r < 4; ++r)
            #pragma unroll
            for (int c = 0; c < 4; ++c) acc[r][c] = b_src[col0 + c];
        for (int ch = 0; ch < XD / 4; ++ch) {
            float4 w[4];
            #pragma unroll
            for (int c = 0; c < 4; ++c)
                w[c] = *(const float4*)(W_src + (col0 + c) * XD + ch * 4);
            #pragma unroll
            for (int r = 0; r < 4; ++r) {
                float4 x = *(const float4*)(&sx[row0 + r][ch * 4]);
                #pragma unroll
                for (int c = 0; c < 4; ++c) {
                    acc[r][c] = fmaf(x.x, w[c].x, acc[r][c]);
                    acc[r][c] = fmaf(x.y, w[c].y, acc[r][c]);
                    acc[r][c] = fmaf(x.z, w[c].z, acc[r][c]);
                    acc[r][c] = fmaf(x.w, w[c].w, acc[r][c]);
                }
            }
        }
        #pragma unroll
        for (int r = 0; r < 4; ++r) {
            float4 g;
            g.x = gelu_exact(acc[r][0]); g.y = gelu_exact(acc[r][1]);
            g.z = gelu_exact(acc[r][2]); g.w = gelu_exact(acc[r][3]);
            *(float4*)(&s_sin[row0 + r][col0]) = g;
        }
    }
    __syncthreads();

    // ---------------- phase 2: GEMM-E (k and v).  8 rows x 4 cols per thread ----------------
    {
        const int cg = tid & 63, rg = tid >> 6;
        const int row0 = rg * 8;
        const float* W; const float* bb; float (*dst)[PAD]; int col0;
        if (cg < 32) { col0 = cg * 4;        W = Wqkv + 128 * HIDN; bb = bqkv + 128; dst = s_k; }
        else         { col0 = (cg - 32) * 4; W = Wqkv + 256 * HIDN; bb = bqkv + 256; dst = s_v; }
        float acc[8][4];
        #pragma unroll
        for (int r = 0; r < 8; ++r)
            #pragma unroll
            for (int c = 0; c < 4; ++c) acc[r][c] = bb[col0 + c];
        for (int ch = 0; ch < HIDN / 4; ++ch) {
            float4 w[4];
            #pragma unroll
            for (int c = 0; c < 4; ++c)
                w[c] = *(const float4*)(W + (col0 + c) * HIDN + ch * 4);
            #pragma unroll
            for (int r = 0; r < 8; ++r) {
                float4 x = *(const float4*)(&s_sin[row0 + r][ch * 4]);
                #pragma unroll
                for (int c = 0; c < 4; ++c) {
                    acc[r][c] = fmaf(x.x, w[c].x, acc[r][c]);
                    acc[r][c] = fmaf(x.y, w[c].y, acc[r][c]);
                    acc[r][c] = fmaf(x.z, w[c].z, acc[r][c]);
                    acc[r][c] = fmaf(x.w, w[c].w, acc[r][c]);
                }
            }
        }
        #pragma unroll
        for (int r = 0; r < 8; ++r) {
            float4 o; o.x = acc[r][0]; o.y = acc[r][1]; o.z = acc[r][2]; o.w = acc[r][3];
            *(float4*)(&dst[row0 + r][col0]) = o;
        }
    }
    __syncthreads();

    // ---------------- phase 3: scores + masked softmax ----------------
    if (tid < NH * KN) {
        const int h = tid >> 5, kk = tid & 31;
        float sc = 0.0f;
        const float4* k4 = (const float4*)(&s_k[kk][h * HD]);
        const float4* q4 = (const float4*)(&s_q[h * HD]);
        #pragma unroll
        for (int d = 0; d < HD / 4; ++d) {
            float4 kv = k4[d]; float4 qv = q4[d];
            sc = fmaf(kv.x, qv.x, sc); sc = fmaf(kv.y, qv.y, sc);
            sc = fmaf(kv.z, qv.z, sc); sc = fmaf(kv.w, qv.w, sc);
        }
        if (mask[n * KN + kk] != 0) sc = -1e30f;   // True => masked out
        s_attn[tid] = sc;
    }
    __syncthreads();
    if (tid < NH) {
        float mx = -1e30f;
        #pragma unroll
        for (int kk = 0; kk < KN; ++kk) mx = fmaxf(mx, s_attn[tid * KN + kk]);
        float den = 0.0f;
        #pragma unroll
        for (int kk = 0; kk < KN; ++kk) den += expf(s_attn[tid * KN + kk] - mx);
        s_mx[tid] = mx; s_den[tid] = 1.0f / den;
    }
    __syncthreads();
    if (tid < NH * KN) {
        const int h = tid >> 5;
        s_attn[tid] = expf(s_attn[tid] - s_mx[h]) * s_den[h];
    }
    __syncthreads();

    // ---------------- phase 4: ctx = attn @ v ----------------
    if (tid < HIDN) {
        const int h = tid >> 5;
        float acc = 0.0f;
        #pragma unroll
        for (int kk = 0; kk < KN; ++kk)
            acc = fmaf(s_attn[h * KN + kk], s_v[kk][tid], acc);
        s_ctx[tid] = acc;
    }
    __syncthreads();

    // ---------------- phase 5: out projection, x2, layernorm ----------------
    if (tid < HIDN) {
        int j = tid;
        float acc = bo[j];
        const float4* w4 = (const float4*)(Wo + j * HIDN);
        const float4* x4 = (const float4*)s_ctx;
        #pragma unroll
        for (int c = 0; c < HIDN / 4; ++c) {
            float4 w = w4[c]; float4 x = x4[c];
            acc = fmaf(w.x, x.x, acc); acc = fmaf(w.y, x.y, acc);
            acc = fmaf(w.z, x.z, acc); acc = fmaf(w.w, x.w, acc);
        }
        s_out[j] = acc * 2.0f;
    }
    __syncthreads();
    if (tid < 64) {
        float a = s_out[tid], b = s_out[tid + 64];
        float s = a + b, ss = a * a + b * b;
        #pragma unroll
        for (int off = 32; off; off >>= 1) {
            s  += __shfl_xor(s, off, 64);
            ss += __shfl_xor(ss, off, 64);
        }
        if (tid == 0) { s_red[0] = s * (1.0f / HIDN); s_red[1] = ss * (1.0f / HIDN); }
    }
    __syncthreads();
    if (tid < HIDN) {
        float mu  = s_red[0];
        float var = s_red[1] - mu * mu;
        float y = (s_out[tid] - mu) * rsqrtf(var + 1e-5f) * ln_g[tid] + ln_b[tid];
        out[n * HIDN + tid] = y;
    }
}

extern "C" void kernel_launch(void* const* d_in, const int* in_sizes, int n_in,
                              void* d_out, int out_size, void* d_ws, size_t ws_size,
                              hipStream_t stream) {
    const float* src    = (const float*)d_in[0];
    const float* dest   = (const float*)d_in[1];
    const int*   adj    = (const int*)  d_in[2];
    const int*   mask   = (const int*)  d_in[3];
    const float* edges  = (const float*)d_in[4];
    const float* W_src  = (const float*)d_in[5];
    const float* b_src  = (const float*)d_in[6];
    const float* W_dest = (const float*)d_in[7];
    const float* b_dest = (const float*)d_in[8];
    const float* Wqkv   = (const float*)d_in[9];
    const float* bqkv   = (const float*)d_in[10];
    const float* Wo     = (const float*)d_in[11];
    const float* bo     = (const float*)d_in[12];
    const float* ln_g   = (const float*)d_in[13];
    const float* ln_b   = (const float*)d_in[14];
    float* outp = (float*)d_out;

    fused_gat_kernel<<<N_DEST, 256, 0, stream>>>(
        src, dest, adj, mask, edges, W_src, b_src, W_dest, b_dest,
        Wqkv, bqkv, Wo, bo, ln_g, ln_b, outp);
}

// Round 2
// 539.332 us; speedup vs baseline: 3.9793x; 3.9793x over previous
//
#include <hip/hip_runtime.h>
#include <math.h>

// Problem constants
#define N_DEST 16000   // B * D_CNT
#define KN     32      // neighbors per dest
#define HIDN   128
#define NH     4
#define HD     32
#define SRCD   64
#define EDGED  16
#define XD     80      // SRCD + EDGED
#define XDP    96      // XD padded to 3 K-tiles of 32
#define SXP    104     // sx LDS row stride (96 + 8), 208B = 13*16
#define SNP    136     // 128-wide LDS row stride (128 + 8), 272B = 17*16
#define G      2       // dest nodes per block

typedef __attribute__((ext_vector_type(8))) short frag8;   // 8 bf16 (4 VGPR)
typedef __attribute__((ext_vector_type(4))) float f32x4;

__device__ __forceinline__ float gelu_exact(float x) {
    return 0.5f * x * (1.0f + erff(x * 0.70710678118654752440f));
}
// bf16 bit helpers (LDS stored as ushort to avoid class-type issues)
__device__ __forceinline__ unsigned short f2bf(float f) {
    union { float f; unsigned int u; } c; c.f = f;
    unsigned int r = c.u + 0x7FFFu + ((c.u >> 16) & 1u);   // RNE
    return (unsigned short)(r >> 16);
}
__device__ __forceinline__ float bf2f(unsigned short h) {
    union { unsigned int u; float f; } c; c.u = ((unsigned int)h) << 16;
    return c.f;
}
__device__ __forceinline__ float bflo(unsigned int u) {
    union { unsigned int u; float f; } c; c.u = u << 16; return c.f;
}
__device__ __forceinline__ float bfhi(unsigned int u) {
    union { unsigned int u; float f; } c; c.u = u & 0xFFFF0000u; return c.f;
}

// ---- prep: convert W_src (pad K 80->96) and Wqkv K/V rows to bf16 in d_ws ----
// ws layout: [0, 128*96)  = Wsb   (W_src padded, row-major 128 x 96)
//            [128*96, +256*128) = Wkvb (Wqkv rows 128..383, row-major 256 x 128)
__global__ void prep_weights(const float* __restrict__ W_src,
                             const float* __restrict__ Wqkv,
                             unsigned short* __restrict__ ws) {
    int i = blockIdx.x * 256 + threadIdx.x;
    if (i < 128 * XDP) {
        int r = i / XDP, c = i - r * XDP;
        ws[i] = f2bf(c < XD ? W_src[r * XD + c] : 0.0f);
    } else {
        int j = i - 128 * XDP;           // < 256*128
        int r = j >> 7, c = j & 127;
        ws[i] = f2bf(Wqkv[(128 + r) * HIDN + c]);
    }
}

__global__ __launch_bounds__(256, 2) void fused_gat_mfma(
    const float* __restrict__ src,    // (16000, 64)
    const float* __restrict__ dest,   // (16000, 64)
    const int*   __restrict__ adj,    // (32, 16000)
    const int*   __restrict__ mask,   // (16000, 32)
    const float* __restrict__ edges,  // (32, 16000, 16)
    const float* __restrict__ b_src,  // (128)
    const float* __restrict__ W_dest, // (128, 64)
    const float* __restrict__ b_dest, // (128)
    const float* __restrict__ Wqkv,   // (384, 128) fp32 (Q rows used here)
    const float* __restrict__ bqkv,   // (384)
    const float* __restrict__ Wo,     // (128, 128)
    const float* __restrict__ bo,     // (128)
    const float* __restrict__ ln_g,
    const float* __restrict__ ln_b,
    const unsigned short* __restrict__ Wsb,   // bf16 128 x 96
    const unsigned short* __restrict__ Wkvb,  // bf16 256 x 128 (K rows 0-127, V rows 128-255)
    float* __restrict__ out)
{
    const int tid = threadIdx.x;
    const int n0  = blockIdx.x * G;

    // sx (gather buffer) is dead once GEMM-D finishes; alias it with k/v.
    __shared__ __align__(16) union {
        unsigned short sx[G * KN][SXP];                      // 13.3 KB
        struct { unsigned short k[G * KN][SNP];              // 17.4 KB
                 unsigned short v[G * KN][SNP]; } kv;        // 17.4 KB
    } u;
    __shared__ __align__(16) unsigned short s_sin[G * KN][SNP];  // 17.4 KB
    __shared__ __align__(16) float s_dest[G][HIDN];
    __shared__ __align__(16) float s_q[G][HIDN];
    __shared__ float s_attn[G][NH][KN];
    __shared__ __align__(16) float s_ctx[G][HIDN];
    __shared__ float s_out[G][HIDN];
    __shared__ float s_red[G][2];

    // ---------------- phase 0: gather x rows (bf16) + dest_in ----------------
    {
        const int row = tid >> 2;            // 0..63  (g*32 + kk)
        const int part = tid & 3;
        const int g = row >> 5, kk = row & 31;
        const int n = n0 + g;
        const int a = adj[kk * N_DEST + n];
        const float* srow = (a == 0) ? nullptr : src + (size_t)(a - 1) * SRCD;
        if (part < 3) {
            const int c0 = part * 20;        // cols [c0, c0+20), pure src
            #pragma unroll
            for (int w = 0; w < 5; ++w) {
                float4 f = srow ? *(const float4*)(srow + c0 + w * 4)
                                : make_float4(0.f, 0.f, 0.f, 0.f);
                u.sx[row][c0 + w * 4 + 0] = f2bf(f.x);
                u.sx[row][c0 + w * 4 + 1] = f2bf(f.y);
                u.sx[row][c0 + w * 4 + 2] = f2bf(f.z);
                u.sx[row][c0 + w * 4 + 3] = f2bf(f.w);
            }
        } else {
            float4 f = srow ? *(const float4*)(srow + 60)
                            : make_float4(0.f, 0.f, 0.f, 0.f);
            u.sx[row][60] = f2bf(f.x); u.sx[row][61] = f2bf(f.y);
            u.sx[row][62] = f2bf(f.z); u.sx[row][63] = f2bf(f.w);
            const float4* ep = (const float4*)(edges + ((size_t)kk * N_DEST + n) * EDGED);
            #pragma unroll
            for (int w = 0; w < 4; ++w) {
                float4 e = ep[w];
                u.sx[row][64 + w * 4 + 0] = f2bf(e.x);
                u.sx[row][64 + w * 4 + 1] = f2bf(e.y);
                u.sx[row][64 + w * 4 + 2] = f2bf(e.z);
                u.sx[row][64 + w * 4 + 3] = f2bf(e.w);
            }
            #pragma unroll
            for (int c = 80; c < XDP; ++c) u.sx[row][c] = 0;   // K-pad zeros
        }
    }
    {
        const int g = tid >> 7, j = tid & 127;
        const int n = n0 + g;
        float acc = b_dest[j];
        const float4* w4 = (const float4*)(W_dest + j * SRCD);
        const float4* x4 = (const float4*)(dest + (size_t)n * SRCD);
        #pragma unroll
        for (int c = 0; c < SRCD / 4; ++c) {
            float4 w = w4[c]; float4 x = x4[c];
            acc = fmaf(w.x, x.x, acc); acc = fmaf(w.y, x.y, acc);
            acc = fmaf(w.z, x.z, acc); acc = fmaf(w.w, x.w, acc);
        }
        s_dest[g][j] = gelu_exact(acc);
    }
    __syncthreads();

    // ---------------- phase 1: q projection (fp32) + GEMM-D via MFMA ----------------
    {
        const int g = tid >> 7, j = tid & 127;
        float acc = bqkv[j];
        const float4* w4 = (const float4*)(Wqkv + (size_t)j * HIDN);
        const float4* x4 = (const float4*)s_dest[g];
        #pragma unroll
        for (int c = 0; c < HIDN / 4; ++c) {
            float4 w = w4[c]; float4 x = x4[c];
            acc = fmaf(w.x, x.x, acc); acc = fmaf(w.y, x.y, acc);
            acc = fmaf(w.z, x.z, acc); acc = fmaf(w.w, x.w, acc);
        }
        s_q[g][j] = acc * 0.17677669529663688110f;   // 1/sqrt(32)
    }
    // GEMM-D: (64 x 96) @ (96 x 128) -> gelu -> s_sin (bf16)
    {
        const int w = tid >> 6, lane = tid & 63;
        const int lg = lane >> 4, lm = lane & 15;
        const int row0 = (w >> 1) * 32, col0 = (w & 1) * 64;
        f32x4 acc[2][4];
        #pragma unroll
        for (int c = 0; c < 4; ++c) {
            float bias = b_src[col0 + c * 16 + lm];
            #pragma unroll
            for (int r = 0; r < 2; ++r) acc[r][c] = (f32x4){bias, bias, bias, bias};
        }
        #pragma unroll
        for (int kt = 0; kt < 3; ++kt) {
            frag8 a[2], b[4];
            #pragma unroll
            for (int r = 0; r < 2; ++r)
                a[r] = *(const frag8*)&u.sx[row0 + r * 16 + lm][kt * 32 + lg * 8];
            #pragma unroll
            for (int c = 0; c < 4; ++c)
                b[c] = *(const frag8*)(Wsb + (size_t)(col0 + c * 16 + lm) * XDP + kt * 32 + lg * 8);
            #pragma unroll
            for (int r = 0; r < 2; ++r)
                #pragma unroll
                for (int c = 0; c < 4; ++c)
                    acc[r][c] = __builtin_amdgcn_mfma_f32_16x16x32_bf16(a[r], b[c], acc[r][c], 0, 0, 0);
        }
        #pragma unroll
        for (int r = 0; r < 2; ++r)
            #pragma unroll
            for (int c = 0; c < 4; ++c)
                #pragma unroll
                for (int e = 0; e < 4; ++e)
                    s_sin[row0 + r * 16 + lg * 4 + e][col0 + c * 16 + lm] =
                        f2bf(gelu_exact(acc[r][c][e]));
    }
    __syncthreads();

    // ---------------- phase 2: GEMM-E (k | v) via MFMA ----------------
    // out 64 x 256: wave w owns cols [w*64, w*64+64); cols 0-127 = K, 128-255 = V
    {
        const int w = tid >> 6, lane = tid & 63;
        const int lg = lane >> 4, lm = lane & 15;
        const int col0 = w * 64;
        f32x4 acc[4][4];
        #pragma unroll
        for (int c = 0; c < 4; ++c) {
            float bias = bqkv[128 + col0 + c * 16 + lm];
            #pragma unroll
            for (int r = 0; r < 4; ++r) acc[r][c] = (f32x4){bias, bias, bias, bias};
        }
        #pragma unroll
        for (int kt = 0; kt < 4; ++kt) {
            frag8 a[4], b[4];
            #pragma unroll
            for (int r = 0; r < 4; ++r)
                a[r] = *(const frag8*)&s_sin[r * 16 + lm][kt * 32 + lg * 8];
            #pragma unroll
            for (int c = 0; c < 4; ++c)
                b[c] = *(const frag8*)(Wkvb + (size_t)(col0 + c * 16 + lm) * HIDN + kt * 32 + lg * 8);
            #pragma unroll
            for (int r = 0; r < 4; ++r)
                #pragma unroll
                for (int c = 0; c < 4; ++c)
                    acc[r][c] = __builtin_amdgcn_mfma_f32_16x16x32_bf16(a[r], b[c], acc[r][c], 0, 0, 0);
        }
        unsigned short (*dst)[SNP] = (col0 < 128) ? u.kv.k : u.kv.v;
        const int cb = col0 & 127;
        #pragma unroll
        for (int r = 0; r < 4; ++r)
            #pragma unroll
            for (int c = 0; c < 4; ++c)
                #pragma unroll
                for (int e = 0; e < 4; ++e)
                    dst[r * 16 + lg * 4 + e][cb + c * 16 + lm] = f2bf(acc[r][c][e]);
    }
    __syncthreads();

    // ---------------- phase 3: scores + masked softmax (fp32 VALU) ----------------
    {
        const int g = tid >> 7, h = (tid >> 5) & 3, kk = tid & 31;
        const int n = n0 + g;
        const int krow = g * 32 + kk;
        const uint4*  kp = (const uint4*)&u.kv.k[krow][h * HD];
        const float4* qp = (const float4*)&s_q[g][h * HD];
        float sc = 0.0f;
        #pragma unroll
        for (int wq = 0; wq < 4; ++wq) {
            uint4 uk = kp[wq];
            float4 q0 = qp[wq * 2], q1 = qp[wq * 2 + 1];
            sc = fmaf(bflo(uk.x), q0.x, sc); sc = fmaf(bfhi(uk.x), q0.y, sc);
            sc = fmaf(bflo(uk.y), q0.z, sc); sc = fmaf(bfhi(uk.y), q0.w, sc);
            sc = fmaf(bflo(uk.z), q1.x, sc); sc = fmaf(bfhi(uk.z), q1.y, sc);
            sc = fmaf(bflo(uk.w), q1.z, sc); sc = fmaf(bfhi(uk.w), q1.w, sc);
        }
        if (mask[n * KN + kk] != 0) sc = -1e30f;
        float mx = sc;
        #pragma unroll
        for (int off = 16; off; off >>= 1) mx = fmaxf(mx, __shfl_xor(mx, off, 32));
        float e = expf(sc - mx);
        float den = e;
        #pragma unroll
        for (int off = 16; off; off >>= 1) den += __shfl_xor(den, off, 32);
        s_attn[g][h][kk] = e / den;
    }
    __syncthreads();

    // ---------------- phase 4: ctx = attn @ v ----------------
    {
        const int g = tid >> 7, d = tid & 127, h = d >> 5;
        float acc = 0.0f;
        #pragma unroll
        for (int kk = 0; kk < KN; ++kk)
            acc = fmaf(s_attn[g][h][kk], bf2f(u.kv.v[g * 32 + kk][d]), acc);
        s_ctx[g][d] = acc;
    }
    __syncthreads();

    // ---------------- phase 5: out projection, x2 ----------------
    {
        const int g = tid >> 7, j = tid & 127;
        float acc = bo[j];
        const float4* w4 = (const float4*)(Wo + (size_t)j * HIDN);
        const float4* x4 = (const float4*)s_ctx[g];
        #pragma unroll
        for (int c = 0; c < HIDN / 4; ++c) {
            float w_ = 0; (void)w_;
            float4 w = w4[c]; float4 x = x4[c];
            acc = fmaf(w.x, x.x, acc); acc = fmaf(w.y, x.y, acc);
            acc = fmaf(w.z, x.z, acc); acc = fmaf(w.w, x.w, acc);
        }
        s_out[g][j] = acc * 2.0f;
    }
    __syncthreads();

    // ---------------- phase 6: layernorm ----------------
    {
        const int w = tid >> 6, lane = tid & 63;
        if (w < G) {
            float a = s_out[w][lane], b = s_out[w][lane + 64];
            float s = a + b, ss = a * a + b * b;
            #pragma unroll
            for (int off = 32; off; off >>= 1) {
                s  += __shfl_xor(s, off, 64);
                ss += __shfl_xor(ss, off, 64);
            }
            if (lane == 0) { s_red[w][0] = s * (1.0f / HIDN); s_red[w][1] = ss * (1.0f / HIDN); }
        }
    }
    __syncthreads();
    {
        const int g = tid >> 7, j = tid & 127;
        float mu  = s_red[g][0];
        float var = s_red[g][1] - mu * mu;
        float y = (s_out[g][j] - mu) * rsqrtf(var + 1e-5f) * ln_g[j] + ln_b[j];
        out[(size_t)(n0 + g) * HIDN + j] = y;
    }
}

extern "C" void kernel_launch(void* const* d_in, const int* in_sizes, int n_in,
                              void* d_out, int out_size, void* d_ws, size_t ws_size,
                              hipStream_t stream) {
    const float* src    = (const float*)d_in[0];
    const float* dest   = (const float*)d_in[1];
    const int*   adj    = (const int*)  d_in[2];
    const int*   mask   = (const int*)  d_in[3];
    const float* edges  = (const float*)d_in[4];
    const float* W_src  = (const float*)d_in[5];
    const float* b_src  = (const float*)d_in[6];
    const float* W_dest = (const float*)d_in[7];
    const float* b_dest = (const float*)d_in[8];
    const float* Wqkv   = (const float*)d_in[9];
    const float* bqkv   = (const float*)d_in[10];
    const float* Wo     = (const float*)d_in[11];
    const float* bo     = (const float*)d_in[12];
    const float* ln_g   = (const float*)d_in[13];
    const float* ln_b   = (const float*)d_in[14];
    float* outp = (float*)d_out;

    unsigned short* ws = (unsigned short*)d_ws;
    const int prep_elems = 128 * XDP + 256 * HIDN;           // 45056
    prep_weights<<<prep_elems / 256, 256, 0, stream>>>(W_src, Wqkv, ws);

    fused_gat_mfma<<<N_DEST / G, 256, 0, stream>>>(
        src, dest, adj, mask, edges, b_src, W_dest, b_dest,
        Wqkv, bqkv, Wo, bo, ln_g, ln_b,
        ws, ws + 128 * XDP, outp);
}